// Round 1
// baseline (91.160 us; speedup 1.0000x reference)
//
#include <hip/hip_runtime.h>
#include <math.h>

// Batched histogram entropy: B rows x 64 int32 tokens, VOCAB=40.
// entropy[b] = -sum_v (c_v/S) * ln(c_v/S + eps), S = 64 + 1e-8.
//
// Telescoping trick: sum_v F(c_v) = sum_elements G[atomic_old], where
// F(c) = c*ln(c/S+eps), G[j] = F(j+1)-F(j). G is a 64-entry LDS table,
// so the hot loop has zero transcendentals and no per-bin loop.

#define NVOCAB 40
#define EPSF 1e-8f

constexpr int BLOCK = 256;
constexpr int WPB = BLOCK / 64;  // waves per block

__global__ __launch_bounds__(BLOCK) void entropy_hist_kernel(
    const int* __restrict__ x, float* __restrict__ out, int total_groups) {
  // G table: 64 floats. hist: per-wave, per-row-in-group (4) private 40-bin histograms.
  __shared__ float G[64];
  __shared__ int hist[WPB][4][NVOCAB];

  const int tid  = threadIdx.x;
  const int lane = tid & 63;
  const int wv   = tid >> 6;
  const int row  = lane >> 4;   // which row of the 4-row group this lane serves
  const int sub  = lane & 15;   // position within the 16-lane row team

  // Build G once per block (2 logf per lane, amortized over thousands of rows).
  if (tid < 64) {
    float c1 = (float)(tid + 1);
    float F1 = c1 * logf(c1 * (1.0f / 64.0f) + EPSF);
    float F0 = 0.0f;
    if (tid > 0) {
      float c0 = (float)tid;
      F0 = c0 * logf(c0 * (1.0f / 64.0f) + EPSF);
    }
    G[tid] = F1 - F0;
  }
  for (int i = tid; i < WPB * 4 * NVOCAB; i += BLOCK) (&hist[0][0][0])[i] = 0;
  __syncthreads();

  int* __restrict__ h = hist[wv][row];

  const int wave_gid    = blockIdx.x * WPB + wv;
  const int total_waves = gridDim.x * WPB;
  const int4* __restrict__ x4 = (const int4*)x;

  // Grid-stride over 4-row groups (1 KiB coalesced load per wave per iter),
  // software-prefetching the next group's int4 to hide HBM latency.
  int g = wave_gid;
  int4 cur = make_int4(0, 0, 0, 0);
  if (g < total_groups) cur = x4[(long)g * 64 + lane];

  while (g < total_groups) {
    const int gn = g + total_waves;
    int4 nxt = make_int4(0, 0, 0, 0);
    if (gn < total_groups) nxt = x4[(long)gn * 64 + lane];

    // Histogram build; ds_add_rtn gives each element a unique "old" count.
    int o0 = atomicAdd(&h[cur.x], 1);
    int o1 = atomicAdd(&h[cur.y], 1);
    int o2 = atomicAdd(&h[cur.z], 1);
    int o3 = atomicAdd(&h[cur.w], 1);

    float s = G[o0] + G[o1] + G[o2] + G[o3];

    // Reset touched bins (DS ops from one wave execute in order; region is
    // wave-private so no cross-wave hazard).
    h[cur.x] = 0; h[cur.y] = 0; h[cur.z] = 0; h[cur.w] = 0;

    // Reduce the 16-lane row team: each team ends with its row's sum_v F(c_v).
    s += __shfl_xor(s, 1, 16);
    s += __shfl_xor(s, 2, 16);
    s += __shfl_xor(s, 4, 16);
    s += __shfl_xor(s, 8, 16);

    // Lanes 0,16,32,48 store 4 contiguous floats (one 16B transaction).
    if (sub == 0) out[g * 4 + row] = s * (-1.0f / 64.0f);

    cur = nxt;
    g = gn;
  }
}

extern "C" void kernel_launch(void* const* d_in, const int* in_sizes, int n_in,
                              void* d_out, int out_size, void* d_ws, size_t ws_size,
                              hipStream_t stream) {
  const int* x = (const int*)d_in[0];
  float* out = (float*)d_out;

  const int n = in_sizes[0];          // B * 64 elements
  const int total_groups = n / 256;   // 4-row groups (B divisible by 4 here)

  int blocks = 2048;                  // 8192 waves -> 8 groups/wave, 32 waves/CU
  const int max_blocks = (total_groups + WPB - 1) / WPB;
  if (blocks > max_blocks) blocks = max_blocks;
  if (blocks < 1) blocks = 1;

  entropy_hist_kernel<<<blocks, BLOCK, 0, stream>>>(x, out, total_groups);
}